// Round 1
// 143.940 us; speedup vs baseline: 1.0383x; 1.0383x over previous
//
#include <hip/hip_runtime.h>
#include <math.h>

#if defined(__has_builtin)
#  if __has_builtin(__builtin_amdgcn_exp2f)
#    define EXP2F(x) __builtin_amdgcn_exp2f(x)
#  endif
#  if __has_builtin(__builtin_amdgcn_rcpf)
#    define RCPF(x) __builtin_amdgcn_rcpf(x)
#  endif
#endif
#ifndef EXP2F
#  define EXP2F(x) exp2f(x)
#endif
#ifndef RCPF
#  define RCPF(x) (1.0f/(x))
#endif

static constexpr int Bn = 16, QN = 512, KN = 512, Hn = 64, DV = 256, DIN = 256;
static constexpr int TQ = 4;                   // R9: 8->4 => 2048 blocks, backfill slack
static constexpr float TWO_LOG2E = 2.8853900817779268f;  // 2*log2(e)
static constexpr float LOG2E     = 1.4426950408889634f;

typedef __attribute__((ext_vector_type(8))) short short8;  // 8 bf16
typedef __attribute__((ext_vector_type(4))) float f32x4;

__device__ __forceinline__ short f2bf(float x) {          // RNE fp32->bf16
  unsigned u = __builtin_bit_cast(unsigned, x);
  u += 0x7FFF + ((u >> 16) & 1);
  return (short)(u >> 16);
}
__device__ __forceinline__ float bf2f(short h) {
  return __builtin_bit_cast(float, ((unsigned)(unsigned short)h) << 16);
}

// Projections via MFMA, 3-pass bf16 hi/lo (R7-verified numerics). R9 changes:
// (a) W packed in-register (prep_kernel folded in: ~+600 VALU/wave, removes a
//     graph node + the wq/wk pack buffers), (b) BOTH q and k outputs written
//     TRANSPOSED ([b][h][n]) through the wave-private tr tile, so attn's
//     q-side reads become block-uniform (scalar-pipe s_load candidates),
// (c) block 0 writes wv2 = 2*wv (drops 64 v_mul per thread-item in attn).
__global__ __launch_bounds__(256) void proj_mfma(
    const float* __restrict__ queries, const float* __restrict__ keys,
    const float* __restrict__ Wq, const float* __restrict__ Wk,
    const float* __restrict__ wv,
    float* __restrict__ qT, float* __restrict__ ekT, float* __restrict__ wv2)
{
  __shared__ float tr[4][16][20];                // 5.1 KB transpose tiles
  int t = threadIdx.x;
  int lane = t & 63, wid = t >> 6;
  if (blockIdx.x == 0 && t < Hn) wv2[t] = 2.0f * wv[t];
  bool is_k = blockIdx.x >= 512;
  int trow = (blockIdx.x & 511) * 16;
  const float* X = is_k ? keys : queries;
  const float* W = is_k ? Wk : Wq;
  float* dT = is_k ? ekT : qT;
  int mr = lane & 15, quad = lane >> 4;
  const float* xp = X + (size_t)(trow + mr) * DIN + quad * 8;
  const float* wp = W + (size_t)(wid * 16 + mr) * DIN + quad * 8;

  f32x4 acc = (f32x4){0.f, 0.f, 0.f, 0.f};
  #pragma unroll
  for (int kc = 0; kc < 8; ++kc) {
    float4 a0 = *(const float4*)(xp + kc * 32);
    float4 a1 = *(const float4*)(xp + kc * 32 + 4);
    float4 b0 = *(const float4*)(wp + kc * 32);
    float4 b1 = *(const float4*)(wp + kc * 32 + 4);
    float av[8] = {a0.x, a0.y, a0.z, a0.w, a1.x, a1.y, a1.z, a1.w};
    float bv[8] = {b0.x, b0.y, b0.z, b0.w, b1.x, b1.y, b1.z, b1.w};
    short8 ah, al, bh, bl;
    #pragma unroll
    for (int j = 0; j < 8; ++j) {
      ah[j] = f2bf(av[j]);
      al[j] = f2bf(av[j] - bf2f(ah[j]));
      bh[j] = f2bf(bv[j]);
      bl[j] = f2bf(bv[j] - bf2f(bh[j]));
    }
    acc = __builtin_amdgcn_mfma_f32_16x16x32_bf16(al, bh, acc, 0, 0, 0);
    acc = __builtin_amdgcn_mfma_f32_16x16x32_bf16(ah, bl, acc, 0, 0, 0);
    acc = __builtin_amdgcn_mfma_f32_16x16x32_bf16(ah, bh, acc, 0, 0, 0);
  }
  // C/D: col = lane&15 (=h_local), row = quad*4 + reg (=n_local)  [verified R4-R8]
  #pragma unroll
  for (int reg = 0; reg < 4; ++reg)              // wave-private tile: no barrier
    tr[wid][mr][quad * 4 + reg] = EXP2F(acc[reg] * TWO_LOG2E);
  int b = trow >> 9, rr = trow & 511;
  #pragma unroll
  for (int hp = 0; hp < 4; ++hp) {
    int h_l = hp * 4 + quad, r_l = mr;
    dT[((size_t)b * Hn + wid * 16 + h_l) * 512 + rr + r_l] = tr[wid][h_l][r_l];
  }
}

// Fused attention — R9 rebalance:
//  * 2048 blocks x 512 thr (TQ=4) against 1024 resident slots (4 blk/CU,
//    wave-limited). Blocks sorted L-DESCENDING (rank = blockIdx>>7 via srank):
//    hardware backfill gives LPT scheduling; tail = one tiny-L block. This
//    replaces the dispatch-assumption-dependent complementary-rank mapping
//    (rocprof: OccupancyPercent 30%, i.e. most wall time was drain).
//  * q-side reads are uniform loads from qT[b][h][q] with b,L readfirstlane'd
//    -> scalar s_load_dwordx4; kills the qes2 LDS stage + 2 ds_read_b128/pair.
//  * tanh(q+k) = 1 - 2/(Eq*Ek+1); paired reciprocals (1 rcp per 2 h);
//    softmax without max-subtraction (|score| <= sum|wv| ~ 7). All math and
//    summation order identical to R8 -> absmax unchanged.
__global__ __launch_bounds__(512) void attn_kernel(
    const float* __restrict__ qT,      // [B,64,512] exp2(C*q) transposed
    const float* __restrict__ ekT,     // [B,64,512] exp2(C*k) transposed
    const float* __restrict__ values,  // [B,512,256]
    const int*   __restrict__ valid_lens,
    const float* __restrict__ wv2,     // [64] = 2*wv
    float* __restrict__ out)           // [B,512,256]
{
  __shared__ __align__(16) float pt[KN][TQ];     // 8 KB  p rows, float4 each
  __shared__ __align__(16) float pacc[TQ][DV];   // 4 KB  upper-half PV partials
  __shared__ float wsum[8][TQ];
  __shared__ float inv_s[TQ];
  __shared__ int srank[Bn];

  int t = threadIdx.x;
  int lane = t & 63, wave = t >> 6;

  // ---- rank table: srank[r] = batch with r-th largest L ----
  if (t < Bn) {
    int Lb = valid_lens[t];
    int r = 0;
    #pragma unroll
    for (int b2 = 0; b2 < Bn; ++b2) {
      int L2 = valid_lens[b2];
      r += (L2 > Lb || (L2 == Lb && b2 < t)) ? 1 : 0;
    }
    srank[r] = t;
  }
  __syncthreads();

  int rank = blockIdx.x >> 7;                    // 0..15, L-descending order
  int b = __builtin_amdgcn_readfirstlane(srank[rank]);   // force SGPR: enables
  int L = __builtin_amdgcn_readfirstlane(valid_lens[b]); // s_load scalarization
  int q0 = (blockIdx.x & 127) * TQ;

  float S = 0.f;                                 // sum_h wv[h] (wv2 = 2*wv)
  #pragma unroll
  for (int h = 0; h < Hn; ++h) S += wv2[h];
  S *= 0.5f;

  // ---- scores: thread owns k = t ----
  {
    int k = t;
    float p[TQ];
    if (k < L) {
      float sc[TQ];
      #pragma unroll
      for (int r = 0; r < TQ; ++r) sc[r] = S;
      const float* kb = ekT + (size_t)b * Hn * KN + k;
      const float* qb = qT  + (size_t)b * Hn * QN + q0;
      for (int h0 = 0; h0 < Hn; h0 += 8) {
        float ekv[8];
        #pragma unroll
        for (int j = 0; j < 8; ++j)              // 8 loads in flight
          ekv[j] = kb[(size_t)(h0 + j) * KN];
        #pragma unroll
        for (int jp = 0; jp < 4; ++jp) {         // paired h: 1 rcp per 2 h
          int ha = h0 + 2 * jp;
          float wa = wv2[ha], wb = wv2[ha + 1];  // uniform -> SGPR
          float4 qa = *(const float4*)(qb + (size_t)ha * QN);        // s_load
          float4 qc = *(const float4*)(qb + (size_t)(ha + 1) * QN);  // s_load
          float eka = ekv[2 * jp], ekb = ekv[2 * jp + 1];
          float da, db, num;
          da = qa.x * eka + 1.0f; db = qc.x * ekb + 1.0f;
          num = wa * db + wb * da; sc[0] -= num * RCPF(da * db);
          da = qa.y * eka + 1.0f; db = qc.y * ekb + 1.0f;
          num = wa * db + wb * da; sc[1] -= num * RCPF(da * db);
          da = qa.z * eka + 1.0f; db = qc.z * ekb + 1.0f;
          num = wa * db + wb * da; sc[2] -= num * RCPF(da * db);
          da = qa.w * eka + 1.0f; db = qc.w * ekb + 1.0f;
          num = wa * db + wb * da; sc[3] -= num * RCPF(da * db);
        }
      }
      #pragma unroll
      for (int r = 0; r < TQ; ++r) p[r] = EXP2F(sc[r] * LOG2E);
      *(float4*)&pt[k][0] = make_float4(p[0], p[1], p[2], p[3]);
    } else {
      #pragma unroll
      for (int r = 0; r < TQ; ++r) p[r] = 0.f;
    }
    #pragma unroll
    for (int r = 0; r < TQ; ++r) {               // in-register row sums
      float s = p[r];
      #pragma unroll
      for (int off = 32; off > 0; off >>= 1) s += __shfl_xor(s, off, 64);
      if (lane == r) wsum[wave][r] = s;
    }
  }
  __syncthreads();
  if (t < TQ) {
    float s = 0.f;
    #pragma unroll
    for (int w = 0; w < 8; ++w) s += wsum[w][t];
    inv_s[t] = 1.0f / s;                         // read after pacc barrier
  }

  // ---- PV: thread owns col c = t&255, half of k (t>>8) ----
  int c = t & (DV - 1), half = t >> 8;
  int mid = L >> 1;
  int k0 = half ? mid : 0;
  int k1 = half ? L : mid;
  float acc[TQ] = {0.f, 0.f, 0.f, 0.f};
  const float* vb = values + (size_t)b * KN * DV + c;
  #pragma unroll 4
  for (int k = k0; k < k1; ++k) {
    float val = vb[(size_t)k * DV];              // coalesced
    float4 pa = *(const float4*)&pt[k][0];       // broadcast
    acc[0] += pa.x * val; acc[1] += pa.y * val;
    acc[2] += pa.z * val; acc[3] += pa.w * val;
  }
  if (half) {
    #pragma unroll
    for (int r = 0; r < TQ; ++r) pacc[r][c] = acc[r];
  }
  __syncthreads();
  if (!half) {
    float* ob = out + (size_t)(b * QN + q0) * DV + c;
    #pragma unroll
    for (int r = 0; r < TQ; ++r)
      ob[(size_t)r * DV] = (acc[r] + pacc[r][c]) * inv_s[r];
  }
}

extern "C" void kernel_launch(void* const* d_in, const int* in_sizes, int n_in,
                              void* d_out, int out_size, void* d_ws, size_t ws_size,
                              hipStream_t stream) {
  const float* queries    = (const float*)d_in[0];
  const float* keys       = (const float*)d_in[1];
  const float* values     = (const float*)d_in[2];
  const int*   valid_lens = (const int*)d_in[3];
  const float* Wq         = (const float*)d_in[4];
  const float* Wk         = (const float*)d_in[5];
  const float* wv         = (const float*)d_in[6];
  float* out = (float*)d_out;

  char* ws = (char*)d_ws;
  float* qT  = (float*)ws;                       // [B,64,512] = 2 MB
  float* ekT = qT + (size_t)Bn * Hn * QN;        // [B,64,512] = 2 MB
  float* wv2 = ekT + (size_t)Bn * Hn * KN;       // [64]

  proj_mfma<<<1024, 256, 0, stream>>>(queries, keys, Wq, Wk, wv, qT, ekT, wv2);
  attn_kernel<<<Bn * (QN / TQ), 512, 0, stream>>>(qT, ekT, values,
                                                  valid_lens, wv2, out);
}